// Round 12
// baseline (4988.491 us; speedup 1.0000x reference)
//
#include <hip/hip_runtime.h>
#include <stdint.h>

// Problem constants
#define Sn 64
#define Un 10
#define Tn 160
#define Fn 80
#define Bn 640      // S*U
#define Hn 768
#define Pn 256
#define En 256
#define G4H 3072
#define NBLK 240    // 3 layers x 5 mt (M=128) x 16 ct

using short8  = __attribute__((ext_vector_type(8))) short;
using floatx4 = __attribute__((ext_vector_type(4))) float;

__device__ __forceinline__ short f2bf(float f){
    unsigned u = __builtin_bit_cast(unsigned, f);
    u += 0x7fffu + ((u >> 16) & 1u);
    return (short)(u >> 16);
}
__device__ __forceinline__ float bf2f(short s){
    return __builtin_bit_cast(float, ((unsigned)(unsigned short)s) << 16);
}
__device__ __forceinline__ float sigm(float x){ return 1.f / (1.f + __expf(-x)); }
__device__ __forceinline__ float tanh_(float x){
    float e = __expf(-2.f * fmaxf(x, -40.f));
    return (1.f - e) / (1.f + e);
}

// async global->LDS DMA, 16B per lane (A tiles).
__device__ __forceinline__ void gll(const short* g, short* l){
    __builtin_amdgcn_global_load_lds(
        (const __attribute__((address_space(1))) unsigned int*)(const void*)g,
        (__attribute__((address_space(3))) unsigned int*)(void*)l, 16, 0, 0);
}
#define VMW(N) asm volatile("s_waitcnt vmcnt(" #N ")" ::: "memory")
#define LGKM0  asm volatile("s_waitcnt lgkmcnt(0)" ::: "memory")

// Packed B layout (register consumption order), per layer, NSTG=KTOT/32:
//   element (ct, s, g, nt, lane, e) at (((ct*NSTG+s)*4+g)*3+nt)*512 + lane*8 + e
// Packed hidden layout (chunk-major, M=128): hid[layer][parity][mt(5)][ch(8)][128][96]

// ---------------- prep: bias sums + Wih0 -> B0 packed tail stages -----------
__global__ void k_prep(const float* __restrict__ Wih0,
                       const float* bi0, const float* bh0,
                       const float* bi1, const float* bh1,
                       const float* bi2, const float* bh2,
                       short* __restrict__ B0, float* __restrict__ bias){
    int i = blockIdx.x * 256 + threadIdx.x;
    const int W0 = G4H * 96;
    if (i < W0){
        int g = i / 96, c = i % 96;            // g: G4H row, k = 768+c
        int gg = g / 768, jj = g % 768;
        int ct = jj / 48, r = jj % 48, ntB = r / 16, lnB = r % 16;
        int k = 768 + c, s = k >> 5, lq = (k >> 3) & 3, e = k & 7;
        size_t off = ((((size_t)(ct * 27 + s)) * 4 + gg) * 3 + ntB) * 512
                   + (size_t)(lq * 16 + lnB) * 8 + e;
        B0[off] = (c < Fn) ? f2bf(Wih0[(size_t)g * Fn + c]) : (short)0;
    } else if (i < W0 + 3 * G4H){
        int j = i - W0; int l = j / G4H, g = j % G4H;
        const float* a = (l == 0) ? bi0 : (l == 1) ? bi1 : bi2;
        const float* b = (l == 0) ? bh0 : (l == 1) ? bh1 : bh2;
        bias[j] = a[g] + b[g];
    }
}

// ---------------- init: zero hidden (bf16) and c (fp32) ---------------------
__global__ void k_init(short* __restrict__ hidden, float* __restrict__ c){
    int i = blockIdx.x * 256 + threadIdx.x;
    int stride = gridDim.x * 256;
    const int NH = 3 * 2 * Bn * Hn;
    const int NC = 3 * Bn * Hn;
    for (int j = i; j < NH; j += stride) hidden[j] = 0;
    for (int j = i; j < NC; j += stride) c[j] = 0.f;
}

// ---------------- fold: out = A @ Whr^T (K=256); packed write if nstg>0 -----
__global__ void k_fold(const float* __restrict__ A, const float* __restrict__ Whr,
                       short* __restrict__ out, int ldout, int coloff, int Mtiles,
                       int nstg){
    int mt = blockIdx.x % Mtiles, nt = blockIdx.x / Mtiles;
    int lane = threadIdx.x & 63;
    int ln = lane & 15, lq = lane >> 4;
    floatx4 acc = {0.f, 0.f, 0.f, 0.f};
    const float* ap = A + (size_t)(mt * 16 + ln) * 256 + lq * 8;
    const float* bp = Whr + (size_t)(lq * 8) * 768 + nt * 16 + ln;
    for (int p0 = 0; p0 < 256; p0 += 32){
        short8 af, bf;
        #pragma unroll
        for (int j = 0; j < 8; ++j) af[j] = f2bf(ap[p0 + j]);
        #pragma unroll
        for (int j = 0; j < 8; ++j) bf[j] = f2bf(bp[(size_t)(p0 + j) * 768]);
        acc = __builtin_amdgcn_mfma_f32_16x16x32_bf16(af, bf, acc, 0, 0, 0);
    }
    #pragma unroll
    for (int r = 0; r < 4; ++r){
        int row = mt * 16 + lq * 4 + r, col = nt * 16 + ln;
        int k = coloff + col;
        if (nstg){
            int gg = row / 768, jj = row % 768;
            int ct = jj / 48, rr = jj % 48, ntB = rr / 16, lnB = rr % 16;
            int s = k >> 5, lqk = (k >> 3) & 3, e = k & 7;
            size_t off = ((((size_t)ct * nstg + s) * 4 + gg) * 3 + ntB) * 512
                       + (size_t)(lqk * 16 + lnB) * 8 + e;
            out[off] = f2bf(acc[r]);
        } else {
            out[(size_t)row * ldout + k] = f2bf(acc[r]);
        }
    }
}

// ---------------- per-wavefront step kernel: M=128, K-split 8-wave ----------
// 240 blocks x 512 thr (1 block/CU, 2 waves/SIMD). layer=bid%3, r2=bid/3:
// mt=r2>>4 (128 rows), ct=r2&15 (48 H-dims). Wave = (gate wg, K-half kh).
// kh=0: chunks 0..7 (L0: 0..4); kh=1: chunks 8..15 (L0: 5..8, ch8 = x).
// Each wave: acc[8][3] partial over its K-half; partials summed in epilogue.
// B: packed -> per-wave contiguous 1KB frags direct to VGPRs (3-slot ring).
// A: per-kh double-buffered 24.5KB rotate-swizzled LDS tiles (gll DMA).
// Steady ledger/wave (in-order): enter [B+0,B+1,B+2]=9; +A(6)=15;
//   ph0 VMW(12) +B=15; ph1 VMW(12) +B=15; ph2 VMW(12) +B=15; end VMW(9).
// Barriers/wave: L0 6|6, L1/2 9|9 (equal across kh - verified; else deadlock).
__global__ __launch_bounds__(512, 2) void k_step(const float* __restrict__ x,
        const short* __restrict__ B0, const short* __restrict__ B1,
        const short* __restrict__ B2, const float* __restrict__ bias,
        short* __restrict__ hidden, float* __restrict__ c, int w){
    __shared__ __align__(16) char smem[98304];  // 4 A-buffers x 24576 B
    short* sAr = (short*)smem;                  // buffer b at b*12288 shorts
    float* sEx = (float*)smem;                  // overlay [8][32][49] fp32

    const int tid = threadIdx.x, lane = tid & 63;
    const int wg = (tid >> 6) & 3, kh = tid >> 8;
    const int bid = blockIdx.x;
    const int layer = bid % 3;
    const int t = w - layer;
    if (t < 0 || t >= Tn) return;
    const int r2 = bid / 3;
    const int mt = r2 >> 4, ct = r2 & 15;
    const int m0 = mt * 128, j0 = ct * 48;
    const short* Bl = (layer == 0) ? B0 : (layer == 1) ? B1 : B2;
    const int NSTG = (layer == 0) ? 27 : 48;
    const int ln = lane & 15, lq = lane >> 4;
    const int pp = (w + 1) & 1;

    const short* bglane = Bl + (size_t)lane * 8;
    const int ctb = ct * NSTG;

    // A DMA lane mapping: unit u=(wg*6+j)*64+lane covers 128 rows x 12 units;
    // LDS unit (row,kc') <- source unit kcg=(kc'-row)%12 (rotate swizzle).
    int aoffA[6];
    #pragma unroll
    for (int j = 0; j < 6; ++j){
        int u = (wg * 6 + j) * 64 + lane;
        int row = u / 12, kcp = u % 12;
        int kcg = kcp - (row % 12); if (kcg < 0) kcg += 12;
        aoffA[j] = row * 96 + kcg * 8;
    }
    int prem[8];
    #pragma unroll
    for (int m8 = 0; m8 < 8; ++m8) prem[m8] = (m8 * 16 + ln) % 12;

    const short* srcA = (layer == 0) ? hidden + (size_t)pp * Bn * Hn
                       : hidden + (size_t)((layer - 1) * 2 + pp) * Bn * Hn;
    const short* srcH = hidden + (size_t)(layer * 2 + pp) * Bn * Hn;

    short8 bfr[3][3];   // register B ring [slot][nt] - slot always literal

#define LOADB(s_, slot_)                                                        \
    {                                                                           \
        const short* p_ = bglane + (size_t)(((ctb) + (s_)) * 12 + wg * 3) * 512;\
        asm volatile("global_load_dwordx4 %0, %1, off"                          \
                     : "=v"(bfr[slot_][0]) : "v"(p_) : "memory");               \
        asm volatile("global_load_dwordx4 %0, %1, off offset:1024"              \
                     : "=v"(bfr[slot_][1]) : "v"(p_) : "memory");               \
        asm volatile("global_load_dwordx4 %0, %1, off offset:2048"              \
                     : "=v"(bfr[slot_][2]) : "v"(p_) : "memory");               \
    }

    auto issueA = [&](int chn){
        const short* src; int chg;
        if (layer == 0 || chn < 8){ src = srcA; chg = chn; }
        else { src = srcH; chg = chn - 8; }
        const short* gb = src + (size_t)(mt * 8 + chg) * 12288;
        short* db = &sAr[(size_t)(2 * kh + (chn & 1)) * 12288];
        #pragma unroll
        for (int j = 0; j < 6; ++j)
            gll(gb + aoffA[j], db + (wg * 6 + j) * 512);
    };

    floatx4 acc[8][3];
    #pragma unroll
    for (int nt = 0; nt < 3; ++nt){
        float bv = (kh == 0) ? bias[layer * G4H + wg * Hn + j0 + nt * 16 + ln] : 0.f;
        #pragma unroll
        for (int m8 = 0; m8 < 8; ++m8){
            acc[m8][nt][0] = bv; acc[m8][nt][1] = bv;
            acc[m8][nt][2] = bv; acc[m8][nt][3] = bv;
        }
    }

// phase k: VMW -> sched_barrier -> afr ds_read -> 24 MFMA (bfr[k]) -> reissue
#define PH(k_, AB_, WAITN, ISSUE)                                               \
    {                                                                           \
        VMW(WAITN);                                                             \
        __builtin_amdgcn_sched_barrier(0);                                      \
        short8 afr[8];                                                          \
        const int ksl_ = (k_) * 4 + lq;                                         \
        _Pragma("unroll")                                                       \
        for (int m8 = 0; m8 < 8; ++m8){                                         \
            int idx = prem[m8] + ksl_; if (idx >= 12) idx -= 12;                \
            afr[m8] = *(const short8*)&sAr[(size_t)(AB_) * 12288 + ((m8 * 16 + ln) * 12 + idx) * 8]; \
        }                                                                       \
        _Pragma("unroll")                                                       \
        for (int m8 = 0; m8 < 8; ++m8)                                          \
            _Pragma("unroll")                                                   \
            for (int nt = 0; nt < 3; ++nt)                                      \
                acc[m8][nt] = __builtin_amdgcn_mfma_f32_16x16x32_bf16(afr[m8], bfr[k_][nt], acc[m8][nt], 0, 0, 0); \
        ISSUE;                                                                  \
    }

    // prologue: first chunk c0 per kh
    const int c0 = (kh == 0) ? 0 : ((layer == 0) ? 5 : 8);
    issueA(c0);
    LOADB(3 * c0 + 0, 0); LOADB(3 * c0 + 1, 1); LOADB(3 * c0 + 2, 2);
    VMW(9);                          // retires A(c0); [B0..B2]=9 remain
    __builtin_amdgcn_s_barrier();

    const int NSTD = (kh == 0) ? ((layer == 0) ? 4 : 7)
                               : ((layer == 0) ? 2 : 7);
    for (int i = 0; i < NSTD; ++i){
        const int ch = c0 + i, s0 = 3 * ch;
        const int ab = 2 * kh + (ch & 1);
        issueA(ch + 1);
        PH(0, ab, 12, LOADB(s0 + 3, 0));
        PH(1, ab, 12, LOADB(s0 + 4, 1));
        PH(2, ab, 12, LOADB(s0 + 5, 2));
        VMW(9);                      // retires A(ch+1); [B+3,B+4,B+5]=9
        __builtin_amdgcn_s_barrier();
    }
    if (layer == 0 && kh == 1){
        // ch7: B loads for ch8, no A-issue (ch8 is x)
        PH(0, 3, 6, LOADB(24, 0));
        PH(1, 3, 6, LOADB(25, 1));
        PH(2, 3, 6, LOADB(26, 2));
        __builtin_amdgcn_s_barrier();
        // x-insert into buffer 2 (kh=1, ch8 parity 0), rotate layout
        {
            int l = tid & 255, rrx = l >> 1, q6 = (l & 1) * 6;
            const float* xr = x + ((size_t)(m0 + rrx) * Tn + t) * Fn;
            #pragma unroll
            for (int ii = 0; ii < 6; ++ii){
                int kcg = q6 + ii, f = kcg * 8;
                short8 v = {0,0,0,0,0,0,0,0};
                if (f < Fn){
                    float4 a = *(const float4*)(xr + f);
                    float4 b = *(const float4*)(xr + f + 4);
                    v[0]=f2bf(a.x); v[1]=f2bf(a.y); v[2]=f2bf(a.z); v[3]=f2bf(a.w);
                    v[4]=f2bf(b.x); v[5]=f2bf(b.y); v[6]=f2bf(b.z); v[7]=f2bf(b.w);
                }
                int kcp = kcg + (rrx % 12); if (kcp >= 12) kcp -= 12;
                *(short8*)&sAr[2 * 12288 + (rrx * 12 + kcp) * 8] = v;
            }
            LGKM0;
            __builtin_amdgcn_s_barrier();
        }
        // ch8 tail (buffer 2)
        PH(0, 2, 6, (void)0);
        PH(1, 2, 3, (void)0);
        PH(2, 2, 0, (void)0);
        __builtin_amdgcn_s_barrier();
    } else if (layer == 0 && kh == 0){
        // tail ch4 (buffer 0)
        PH(0, 0, 6, (void)0);
        PH(1, 0, 3, (void)0);
        PH(2, 0, 0, (void)0);
        __builtin_amdgcn_s_barrier();
        // align with kh=1's extra x-insert barrier? No: kh0=1+4+1=6, kh1=1+2+1+1+1=6. OK.
    } else {
        // L1/2 tail: kh=0 ch7 (buf 1), kh=1 ch15 (buf 3)
        const int ab = 2 * kh + 1;
        PH(0, ab, 6, (void)0);
        PH(1, ab, 3, (void)0);
        PH(2, ab, 0, (void)0);
        __builtin_amdgcn_s_barrier();
    }
#undef PH
#undef LOADB

    // ---- epilogue: combine K-half partials, cell update (sEx overlays sAr) ----
    #pragma unroll
    for (int p = 0; p < 4; ++p){
        if (p) __syncthreads();
        #pragma unroll
        for (int mm = 0; mm < 2; ++mm){
            #pragma unroll
            for (int nt = 0; nt < 3; ++nt)
                #pragma unroll
                for (int r = 0; r < 4; ++r)
                    sEx[((size_t)(kh * 4 + wg) * 32 + mm * 16 + lq * 4 + r) * 49
                        + nt * 16 + ln] = acc[2 * p + mm][nt][r];
        }
        __syncthreads();
        {
            int r32 = tid >> 4, cb3 = (tid & 15) * 3;
            int row = p * 32 + r32;
            float* cp = c + ((size_t)layer * Bn + (m0 + row)) * Hn + j0 + cb3;
            short* hbase = hidden + (size_t)(layer * 2 + (w & 1)) * Bn * Hn;
            short* hp = hbase + ((size_t)(mt * 8 + (ct >> 1)) * 128 + row) * 96
                      + (ct & 1) * 48 + cb3;
            #pragma unroll
            for (int ii = 0; ii < 3; ++ii){
                int cc_ = cb3 + ii;
                float gi = sEx[(0 * 32 + r32) * 49 + cc_] + sEx[(4 * 32 + r32) * 49 + cc_];
                float gf = sEx[(1 * 32 + r32) * 49 + cc_] + sEx[(5 * 32 + r32) * 49 + cc_];
                float gg = sEx[(2 * 32 + r32) * 49 + cc_] + sEx[(6 * 32 + r32) * 49 + cc_];
                float go = sEx[(3 * 32 + r32) * 49 + cc_] + sEx[(7 * 32 + r32) * 49 + cc_];
                float cv = sigm(gf) * cp[ii] + sigm(gi) * tanh_(gg);
                cp[ii] = cv;
                hp[ii] = f2bf(sigm(go) * tanh_(cv));
            }
        }
    }
}

// ---------------- final: emb = normalize(relu(hidden2_last @ Wf^T + b)) -----
__global__ void k_final(const short* __restrict__ h2, const short* __restrict__ Wf,
                        const float* __restrict__ blin, float* __restrict__ out){
    __shared__ __align__(16) short sH[768];
    __shared__ float sW[4];
    int b = blockIdx.x, e = threadIdx.x;
    if (e < 96){
        int mtb = b >> 7, rowb = b & 127;
        *(short8*)&sH[e * 8] = *(const short8*)
            &h2[((size_t)(mtb * 8 + e / 12) * 128 + rowb) * 96 + (e % 12) * 8];
    }
    __syncthreads();
    float acc = blin[e];
    const short* wr = Wf + (size_t)e * 768;
    for (int j = 0; j < 768; j += 8){
        short8 hv = *(const short8*)&sH[j];
        short8 wv = *(const short8*)&wr[j];
        #pragma unroll
        for (int k = 0; k < 8; ++k) acc += bf2f(hv[k]) * bf2f(wv[k]);
    }
    float v = fmaxf(acc, 0.f);
    float s = v * v;
    #pragma unroll
    for (int off = 32; off >= 1; off >>= 1) s += __shfl_down(s, off);
    if ((e & 63) == 0) sW[e >> 6] = s;
    __syncthreads();
    float tot = sW[0] + sW[1] + sW[2] + sW[3];
    float scale = 1.f / fmaxf(sqrtf(tot), 1e-12f);
    out[(size_t)b * 256 + e] = v * scale;
}

// ---------------- host launcher ---------------------------------------------
extern "C" void kernel_launch(void* const* d_in, const int* in_sizes, int n_in,
                              void* d_out, int out_size, void* d_ws, size_t ws_size,
                              hipStream_t stream){
    const float* x    = (const float*)d_in[0];
    const float* Wih0 = (const float*)d_in[1];
    const float* Whh0 = (const float*)d_in[2];
    const float* bi0  = (const float*)d_in[3];
    const float* bh0  = (const float*)d_in[4];
    const float* Whr0 = (const float*)d_in[5];
    const float* Wih1 = (const float*)d_in[6];
    const float* Whh1 = (const float*)d_in[7];
    const float* bi1  = (const float*)d_in[8];
    const float* bh1  = (const float*)d_in[9];
    const float* Whr1 = (const float*)d_in[10];
    const float* Wih2 = (const float*)d_in[11];
    const float* Whh2 = (const float*)d_in[12];
    const float* bi2  = (const float*)d_in[13];
    const float* bh2  = (const float*)d_in[14];
    const float* Whr2 = (const float*)d_in[15];
    const float* Wlin = (const float*)d_in[16];
    const float* blin = (const float*)d_in[17];

    char* wp = (char*)d_ws;
    size_t off = 0;
    auto alloc = [&](size_t bytes) -> char* {
        char* p = wp + off; off += (bytes + 255) & ~(size_t)255; return p;
    };
    short* B0   = (short*)alloc((size_t)G4H * 864 * 2);
    short* B1   = (short*)alloc((size_t)G4H * 1536 * 2);
    short* B2   = (short*)alloc((size_t)G4H * 1536 * 2);
    short* Wf   = (short*)alloc((size_t)256 * 768 * 2);
    float* bias = (float*)alloc((size_t)3 * G4H * 4);
    short* hid  = (short*)alloc((size_t)3 * 2 * Bn * Hn * 2);
    float* cst  = (float*)alloc((size_t)3 * Bn * Hn * 4);

    hipLaunchKernelGGL(k_prep, dim3(1188), dim3(256), 0, stream,
                       Wih0, bi0, bh0, bi1, bh1, bi2, bh2, B0, bias);
    hipLaunchKernelGGL(k_init, dim3(1024), dim3(256), 0, stream, hid, cst);
    // folds (packed): R_l = Whh_l @ Whr_l ; U_l = Wih_l @ Whr_{l-1}
    hipLaunchKernelGGL(k_fold, dim3(192 * 48), dim3(64), 0, stream, Whh0, Whr0, B0, 0, 0,   192, 27);
    hipLaunchKernelGGL(k_fold, dim3(192 * 48), dim3(64), 0, stream, Wih1, Whr0, B1, 0, 0,   192, 48);
    hipLaunchKernelGGL(k_fold, dim3(192 * 48), dim3(64), 0, stream, Whh1, Whr1, B1, 0, 768, 192, 48);
    hipLaunchKernelGGL(k_fold, dim3(192 * 48), dim3(64), 0, stream, Wih2, Whr1, B2, 0, 0,   192, 48);
    hipLaunchKernelGGL(k_fold, dim3(192 * 48), dim3(64), 0, stream, Whh2, Whr2, B2, 0, 768, 192, 48);
    // Wf stays linear (k_final reads row-major)
    hipLaunchKernelGGL(k_fold, dim3(16 * 48), dim3(64), 0, stream, Wlin, Whr2, Wf, 768, 0, 16, 0);

    for (int w = 0; w < 162; ++w)
        hipLaunchKernelGGL(k_step, dim3(NBLK), dim3(512), 0, stream,
                           x, B0, B1, B2, bias, hid, cst, w);

    const short* h2 = hid + (size_t)5 * Bn * Hn;   // layer 2, parity 1, chunk-major
    hipLaunchKernelGGL(k_final, dim3(Bn), dim3(256), 0, stream, h2, Wf, blin, (float*)d_out);
}